// Round 10
// baseline (868.548 us; speedup 1.0000x reference)
//
#include <hip/hip_runtime.h>
#include <hip/hip_bf16.h>

#define H_     32
#define D_     128
#define HID_   4096
#define DOFF_  1024
#define BD_    32
#define T_     1056
#define MAXKV_ 513
#define R_     16
#define NA_    4
#define SCALE_ 0.08838834764831845f  /* 1/sqrt(128) */

typedef __attribute__((ext_vector_type(8))) short short8;
typedef __attribute__((ext_vector_type(4))) float f32x4;

__device__ __forceinline__ float toF(float x) { return x; }
__device__ __forceinline__ float toF(__hip_bfloat16 x) { return __bfloat162float(x); }
__device__ __forceinline__ void storev(float* p, float v) { *p = v; }
__device__ __forceinline__ void storev(__hip_bfloat16* p, float v) { *p = __float2bfloat16(v); }

__device__ __forceinline__ void gload16(const void* g, void* l) {
  __builtin_amdgcn_global_load_lds(
      (const __attribute__((address_space(1))) unsigned int*)g,
      (__attribute__((address_space(3))) unsigned int*)l, 16, 0, 0);
}

__device__ __forceinline__ void load4(const float* p, float* v) {
  float4 t = *(const float4*)p;
  v[0] = t.x; v[1] = t.y; v[2] = t.z; v[3] = t.w;
}
__device__ __forceinline__ void load4(const __hip_bfloat16* p, float* v) {
  short4 t = *(const short4*)p;
  const __hip_bfloat16* e = (const __hip_bfloat16*)&t;
  v[0] = toF(e[0]); v[1] = toF(e[1]); v[2] = toF(e[2]); v[3] = toF(e[3]);
}

// ---------------------------------------------------------------------------
// fp32 -> bf16 elementwise cast
// ---------------------------------------------------------------------------
__global__ __launch_bounds__(256) void cast_bf16_kernel(
    const float* __restrict__ X, __hip_bfloat16* __restrict__ Y, int n4) {
  int i = blockIdx.x * 256 + threadIdx.x;
  if (i >= n4) return;
  float4 v = ((const float4*)X)[i];
  __hip_bfloat16 o[4] = {__float2bfloat16(v.x), __float2bfloat16(v.y),
                         __float2bfloat16(v.z), __float2bfloat16(v.w)};
  *(short4*)(Y + (size_t)i * 4) = *(short4*)o;
}

// ---------------------------------------------------------------------------
// 4 weights W[K][N] fp32 -> WT4[z][N][K] bf16 in one launch (grid.z picks W).
// ---------------------------------------------------------------------------
__global__ __launch_bounds__(256) void transpose_cast4_kernel(
    const float* __restrict__ W0, const float* __restrict__ W1,
    const float* __restrict__ W2, const float* __restrict__ W3,
    __hip_bfloat16* __restrict__ WT4) {
  __shared__ float tile[64][65];
  const float* W = blockIdx.z == 0 ? W0 : (blockIdx.z == 1 ? W1
                   : (blockIdx.z == 2 ? W2 : W3));
  __hip_bfloat16* WT = WT4 + (size_t)blockIdx.z * HID_ * HID_;
  int tx = threadIdx.x & 15;   // 4-elem chunk
  int ty = threadIdx.x >> 4;   // 0..15
  int r0 = blockIdx.y * 64, c0 = blockIdx.x * 64;
#pragma unroll
  for (int s = 0; s < 64; s += 16) {
    float4 v = *(const float4*)(W + (size_t)(r0 + ty + s) * HID_ + c0 + tx * 4);
    tile[ty + s][tx * 4 + 0] = v.x;
    tile[ty + s][tx * 4 + 1] = v.y;
    tile[ty + s][tx * 4 + 2] = v.z;
    tile[ty + s][tx * 4 + 3] = v.w;
  }
  __syncthreads();
#pragma unroll
  for (int s = 0; s < 64; s += 16) {
    int c = ty + s;
    __hip_bfloat16 o[4];
#pragma unroll
    for (int e = 0; e < 4; ++e) o[e] = __float2bfloat16(tile[tx * 4 + e][c]);
    *(short4*)(WT + (size_t)(c0 + c) * HID_ + r0 + tx * 4) = *(short4*)o;
  }
}

// ---------------------------------------------------------------------------
// u[t][r] = x[t] . WA[aid(t)][:,r]; blockIdx.y selects which of 3 (WA,U) pairs.
// ---------------------------------------------------------------------------
template <typename XT>
__global__ __launch_bounds__(256) void lora_u_kernel(
    const XT* __restrict__ X, const float* __restrict__ WA0,
    const float* __restrict__ WA1, const float* __restrict__ WA2,
    const int* __restrict__ segment, float* __restrict__ U0,
    float* __restrict__ U1, float* __restrict__ U2) {
  int t = blockIdx.x;
  int tid = threadIdx.x;
  const float* WA = blockIdx.y == 0 ? WA0 : (blockIdx.y == 1 ? WA1 : WA2);
  float* U = blockIdx.y == 0 ? U0 : (blockIdx.y == 1 ? U1 : U2);

  int aid = 0;
#pragma unroll
  for (int i = 1; i < NA_; ++i)
    if (t >= segment[i]) aid = i;

  const XT* x = X + (size_t)t * HID_;
  const float* wa = WA + (size_t)aid * HID_ * R_;

  float part[R_];
#pragma unroll
  for (int r = 0; r < R_; ++r) part[r] = 0.f;

  for (int h = tid * 4; h < HID_; h += 1024) {
    float xv[4];
    load4(x + h, xv);
#pragma unroll
    for (int e = 0; e < 4; ++e) {
      const float* w = wa + (size_t)(h + e) * R_;
#pragma unroll
      for (int r = 0; r < R_; ++r) part[r] += xv[e] * w[r];
    }
  }

  __shared__ float red[256][R_ + 1];
#pragma unroll
  for (int r = 0; r < R_; ++r) red[tid][r] = part[r];
  __syncthreads();
  for (int s = 128; s > 0; s >>= 1) {
    if (tid < s) {
#pragma unroll
      for (int r = 0; r < R_; ++r) red[tid][r] += red[tid + s][r];
    }
    __syncthreads();
  }
  if (tid < R_) U[(size_t)t * R_ + tid] = red[0][tid];
}

// ---------------------------------------------------------------------------
// GEMM: Y[t][n] = Xb[t].W[:,n] + LoRA. bf16 MFMA, 256x256 tile, BK=32,
// 512 threads / 8 waves (2Mx4N, each wave 128x64, acc[8][4]).
// 4-deep LDS pipeline (prefetch distance 3) with raw s_barrier + counted
// vmcnt(12): stage s+3, wait for stage s's 4 loads only (12 newer in flight).
// Covers ~900cy HBM latency with ~3 phases of MFMA. LDS = 128 KB.
// Multi-matrix: blockIdx.x spans nmat*16 n-tiles. nwg % 8 == 0 (XCD swizzle).
// ---------------------------------------------------------------------------
#define ASTG 8192   /* elems per A stage: 256 rows x 32 k */

template <typename OUT_T>
__global__ __launch_bounds__(512, 2) void gemm_bf16_lora_kernel(
    const __hip_bfloat16* __restrict__ Xb, const __hip_bfloat16* __restrict__ WT4,
    const float* __restrict__ U0, const float* __restrict__ U1,
    const float* __restrict__ U2, const float* __restrict__ B0,
    const float* __restrict__ B1, const float* __restrict__ B2,
    const int* __restrict__ segment, OUT_T* __restrict__ Y0,
    OUT_T* __restrict__ Y1, OUT_T* __restrict__ Y2, int Trows) {
  __shared__ __hip_bfloat16 As[4 * ASTG];   // 64 KB
  __shared__ __hip_bfloat16 Bs[4 * ASTG];   // 64 KB

  // XCD-aware bijective remap of the flat block id
  const int nwg = gridDim.x * gridDim.y;
  const int flat = blockIdx.y * gridDim.x + blockIdx.x;
  const int swz = (flat & 7) * (nwg >> 3) + (flat >> 3);
  const int bx = swz % gridDim.x;
  const int by = swz / gridDim.x;
  const int w = bx >> 4;             // which matrix (16 n-tiles of 256 each)
  const int n0 = (bx & 15) * 256;
  const int m0 = by * 256;

  const __hip_bfloat16* WT = WT4 + (size_t)w * HID_ * HID_;
  const float* U = w == 0 ? U0 : (w == 1 ? U1 : U2);
  const float* BMAT = w == 0 ? B0 : (w == 1 ? B1 : B2);
  OUT_T* Y = w == 0 ? Y0 : (w == 1 ? Y1 : Y2);

  const int tid = threadIdx.x;
  const int lane = tid & 63;
  const int wave = tid >> 6;          // 0..7
  const int wr = (wave >> 2) * 128;   // 0 / 128
  const int wc = (wave & 3) * 64;     // 0 / 64 / 128 / 192

  // staging: 512 threads x 16B = 8KB = 128 rows x 32k per instruction
  const int srow = tid >> 2;          // 0..127
  const int sel = (tid & 3) * 8;
  int ar0 = m0 + srow;       if (ar0 >= Trows) ar0 = Trows - 1;
  int ar1 = m0 + 128 + srow; if (ar1 >= Trows) ar1 = Trows - 1;
  const __hip_bfloat16* gA0 = Xb + (size_t)ar0 * HID_ + sel;
  const __hip_bfloat16* gA1 = Xb + (size_t)ar1 * HID_ + sel;
  const __hip_bfloat16* gB0 = WT + (size_t)(n0 + srow) * HID_ + sel;
  const __hip_bfloat16* gB1 = WT + (size_t)(n0 + 128 + srow) * HID_ + sel;

  const int lrow = lane & 15;
  const int lk = (lane >> 4) * 8;
  const int fAo = (wr + lrow) * 32 + lk;
  const int fBo = (wc + lrow) * 32 + lk;

  f32x4 acc[8][4] = {};

#define STAGE_(B, koff)                                        \
  do {                                                         \
    __hip_bfloat16* a_ = As + (B) * ASTG;                      \
    __hip_bfloat16* b_ = Bs + (B) * ASTG;                      \
    gload16(gA0 + (koff), a_ + tid * 8);                       \
    gload16(gA1 + (koff), a_ + 4096 + tid * 8);                \
    gload16(gB0 + (koff), b_ + tid * 8);                       \
    gload16(gB1 + (koff), b_ + 4096 + tid * 8);                \
  } while (0)

#define COMPUTE_(B)                                                          \
  do {                                                                       \
    const __hip_bfloat16* aB_ = As + (B) * ASTG;                             \
    const __hip_bfloat16* bB_ = Bs + (B) * ASTG;                             \
    short8 a[8], b[4];                                                       \
    _Pragma("unroll") for (int mi = 0; mi < 8; ++mi)                         \
        a[mi] = *(const short8*)(aB_ + fAo + mi * 512);                      \
    _Pragma("unroll") for (int ni = 0; ni < 4; ++ni)                         \
        b[ni] = *(const short8*)(bB_ + fBo + ni * 512);                      \
    _Pragma("unroll") for (int mi = 0; mi < 8; ++mi)                         \
        _Pragma("unroll") for (int ni = 0; ni < 4; ++ni)                     \
            acc[mi][ni] = __builtin_amdgcn_mfma_f32_16x16x32_bf16(           \
                a[mi], b[ni], acc[mi][ni], 0, 0, 0);                         \
  } while (0)

  // prologue: fill 3 stages ahead
  STAGE_(0, 0);
  STAGE_(1, 32);
  STAGE_(2, 64);

  // steady state: steps s = 0 .. 124 (of 128); stage s+3, compute s
  for (int s = 0; s < 125; ++s) {
    STAGE_((s + 3) & 3, 96 + s * 32);
    asm volatile("s_waitcnt vmcnt(12)" ::: "memory");  // stage s landed
    __builtin_amdgcn_s_barrier();
    asm volatile("" ::: "memory");
    COMPUTE_(s & 3);
    asm volatile("" ::: "memory");
    __builtin_amdgcn_s_barrier();
  }
  // tail: steps 125 (buf 1), 126 (buf 2), 127 (buf 3)
  asm volatile("s_waitcnt vmcnt(8)" ::: "memory");
  __builtin_amdgcn_s_barrier();
  asm volatile("" ::: "memory");
  COMPUTE_(1);
  asm volatile("" ::: "memory");
  __builtin_amdgcn_s_barrier();
  asm volatile("s_waitcnt vmcnt(4)" ::: "memory");
  __builtin_amdgcn_s_barrier();
  asm volatile("" ::: "memory");
  COMPUTE_(2);
  asm volatile("" ::: "memory");
  __builtin_amdgcn_s_barrier();
  asm volatile("s_waitcnt vmcnt(0)" ::: "memory");
  __builtin_amdgcn_s_barrier();
  asm volatile("" ::: "memory");
  COMPUTE_(3);

#undef STAGE_
#undef COMPUTE_

  const int crow = (lane >> 4) * 4;
  const int ccol = lane & 15;
#pragma unroll
  for (int mi = 0; mi < 8; ++mi) {
    const int tb = m0 + wr + mi * 16 + crow;
#pragma unroll
    for (int i = 0; i < 4; ++i) {
      const int t = tb + i;
      if (t >= Trows) continue;
      int aid = 0;
#pragma unroll
      for (int s = 1; s < NA_; ++s)
        if (t >= segment[s]) aid = s;
      const float* ub = U + (size_t)t * R_;
      const float* bb = BMAT + (size_t)aid * R_ * HID_;
#pragma unroll
      for (int ni = 0; ni < 4; ++ni) {
        const int n = n0 + wc + ni * 16 + ccol;
        float v = acc[mi][ni][i];
        const float* bc = bb + n;
#pragma unroll
        for (int r = 0; r < R_; ++r) v += ub[r] * bc[(size_t)r * HID_];
        storev(Y + (size_t)t * HID_ + n, v);
      }
    }
  }
}

// ---------------------------------------------------------------------------
// MFMA flash prefill. Block = 64 queries x 1 head, 4 waves x 16 q-rows.
// ---------------------------------------------------------------------------
#define QB 64
#define KB 32

__global__ __launch_bounds__(256) void attn_prefill_mfma_kernel(
    const __hip_bfloat16* __restrict__ qp, const __hip_bfloat16* __restrict__ kp,
    const __hip_bfloat16* __restrict__ vp, const int* __restrict__ indptr,
    __hip_bfloat16* __restrict__ attn) {
  __shared__ __hip_bfloat16 Klds[KB * 128];     // XOR-swizzled (chunk ^= row&7)
  __shared__ __hip_bfloat16 Vt[128 * 40];       // Vt[d][k], rows padded to 40
  __shared__ __hip_bfloat16 Plds[4][16 * 40];   // per-wave P, rows padded to 40

  const int nwg = gridDim.x * gridDim.y;
  const int flat = blockIdx.y * gridDim.x + blockIdx.x;
  const int swz = (flat & 7) * (nwg >> 3) + (flat >> 3);
  const int q0 = (swz % gridDim.x) * QB;
  const int h = swz / gridDim.x;

  const int tid = threadIdx.x;
  const int lane = tid & 63;
  const int wave = tid >> 6;
  const int g = lane >> 4;
  const int lc = lane & 15;

  int qrows[4], qstart[4];
#pragma unroll
  for (int i = 0; i < 4; ++i) {
    int q = q0 + wave * 16 + g * 4 + i;
    qrows[i] = q;
    int s0 = 0;
#pragma unroll
    for (int j = 1; j < NA_; ++j)
      if (q >= indptr[j]) s0 = indptr[j];
    qstart[i] = s0;
  }

  short8 aq[4];
  {
    const __hip_bfloat16* qrow = qp + (size_t)(q0 + wave * 16 + lc) * HID_ + h * D_;
#pragma unroll
    for (int dc = 0; dc < 4; ++dc)
      aq[dc] = *(const short8*)(qrow + dc * 32 + g * 8);
  }

  float mrow[4], lrow[4];
#pragma unroll
  for (int i = 0; i < 4; ++i) { mrow[i] = -1e30f; lrow[i] = 0.f; }
  f32x4 o[8] = {};

  int ks0 = 0;
#pragma unroll
  for (int j = 1; j < NA_; ++j)
    if (q0 >= indptr[j]) ks0 = indptr[j];
  const int kt0 = ks0 & ~(KB - 1);

  const int sr = tid >> 4;
  const int sc = tid & 15;

  for (int kt = kt0; kt < q0 + QB; kt += KB) {
    gload16(kp + (size_t)(kt + sr) * HID_ + h * D_ + ((sc ^ (sr & 7)) * 8),
            Klds + tid * 8);
    gload16(kp + (size_t)(kt + 16 + sr) * HID_ + h * D_ + ((sc ^ (sr & 7)) * 8),
            Klds + 2048 + tid * 8);
    {
      short8 v0 = *(const short8*)(vp + (size_t)(kt + sr) * HID_ + h * D_ + sc * 8);
      short8 v1 = *(const short8*)(vp + (size_t)(kt + 16 + sr) * HID_ + h * D_ + sc * 8);
      const __hip_bfloat16* e0 = (const __hip_bfloat16*)&v0;
      const __hip_bfloat16* e1 = (const __hip_bfloat16*)&v1;
#pragma unroll
      for (int e = 0; e < 8; ++e) {
        Vt[(sc * 8 + e) * 40 + sr] = e0[e];
        Vt[(sc * 8 + e) * 40 + sr + 16] = e1[e];
      }
    }
    __syncthreads();

    f32x4 s0v = {}, s1v = {};
#pragma unroll
    for (int dc = 0; dc < 4; ++dc) {
      const int cb = dc * 4 + g;
      short8 bk0 = *(const short8*)(Klds + lc * 128 + ((cb ^ (lc & 7)) * 8));
      short8 bk1 = *(const short8*)(Klds + (16 + lc) * 128 + ((cb ^ (lc & 7)) * 8));
      s0v = __builtin_amdgcn_mfma_f32_16x16x32_bf16(aq[dc], bk0, s0v, 0, 0, 0);
      s1v = __builtin_amdgcn_mfma_f32_16x16x32_bf16(aq[dc], bk1, s1v, 0, 0, 0);
    }

    const int kl0 = kt + lc, kl1 = kt + 16 + lc;
#pragma unroll
    for (int i = 0; i < 4; ++i) {
      float sm0 = s0v[i] * SCALE_;
      float sm1 = s1v[i] * SCALE_;
      bool v0ok = (kl0 >= qstart[i]) && (kl0 <= qrows[i]);
      bool v1ok = (kl1 >= qstart[i]) && (kl1 <= qrows[i]);
      float mx = fmaxf(v0ok ? sm0 : -1e30f, v1ok ? sm1 : -1e30f);
#pragma unroll
      for (int off = 1; off < 16; off <<= 1)
        mx = fmaxf(mx, __shfl_xor(mx, off));
      float mnew = fmaxf(mrow[i], mx);
      float alpha = __expf(mrow[i] - mnew);
      float p0 = v0ok ? __expf(sm0 - mnew) : 0.f;
      float p1 = v1ok ? __expf(sm1 - mnew) : 0.f;
      lrow[i] = lrow[i] * alpha + p0 + p1;
      mrow[i] = mnew;
#pragma unroll
      for (int dc = 0; dc < 8; ++dc) o[dc][i] *= alpha;
      Plds[wave][(g * 4 + i) * 40 + lc] = __float2bfloat16(p0);
      Plds[wave][(g * 4 + i) * 40 + 16 + lc] = __float2bfloat16(p1);
    }

    asm volatile("s_waitcnt lgkmcnt(0)" ::: "memory");

    short8 ap = *(const short8*)(&Plds[wave][lc * 40 + g * 8]);
#pragma unroll
    for (int dc = 0; dc < 8; ++dc) {
      short8 bv = *(const short8*)(&Vt[(dc * 16 + lc) * 40 + g * 8]);
      o[dc] = __builtin_amdgcn_mfma_f32_16x16x32_bf16(ap, bv, o[dc], 0, 0, 0);
    }
    __syncthreads();
  }

#pragma unroll
  for (int i = 0; i < 4; ++i) {
    float l = lrow[i];
#pragma unroll
    for (int off = 1; off < 16; off <<= 1) l += __shfl_xor(l, off);
    lrow[i] = 1.f / l;
  }
#pragma unroll
  for (int dc = 0; dc < 8; ++dc)
#pragma unroll
    for (int i = 0; i < 4; ++i)
      attn[(size_t)qrows[i] * HID_ + h * D_ + dc * 16 + lc] =
          __float2bfloat16(o[dc][i] * lrow[i]);
}

// ---------------------------------------------------------------------------
// Paged decode attention (4 waves split keys; appended token from kp/vp).
// ---------------------------------------------------------------------------
__global__ __launch_bounds__(256) void attn_decode_kernel(
    const __hip_bfloat16* __restrict__ qp, const __hip_bfloat16* __restrict__ kp,
    const __hip_bfloat16* __restrict__ vp, const float* __restrict__ kcache,
    const float* __restrict__ vcache, const int* __restrict__ kv_lens,
    __hip_bfloat16* __restrict__ attn) {
  int h = blockIdx.x;
  int b = blockIdx.y;
  int wave = threadIdx.x >> 6;
  int lane = threadIdx.x & 63;
  int t = DOFF_ + b;

  const __hip_bfloat16* qptr = qp + (size_t)t * HID_ + h * D_;
  float q0 = toF(qptr[lane]), q1 = toF(qptr[lane + 64]);
  int len = kv_lens[b];

  int cnt = len + 1;
  int chunk = (cnt + 3) >> 2;
  int ks = wave * chunk;
  int ke = ks + chunk; if (ke > cnt) ke = cnt;

  float m = -1e30f, l = 0.f, acc0 = 0.f, acc1 = 0.f;
  for (int k = ks; k < ke; ++k) {
    float kv0, kv1, vv0, vv1;
    if (k == len) {
      const __hip_bfloat16* kptr = kp + (size_t)t * HID_ + h * D_;
      const __hip_bfloat16* vptr = vp + (size_t)t * HID_ + h * D_;
      kv0 = toF(kptr[lane]); kv1 = toF(kptr[lane + 64]);
      vv0 = toF(vptr[lane]); vv1 = toF(vptr[lane + 64]);
    } else {
      size_t base = (((size_t)b * MAXKV_ + k) * H_ + h) * D_;
      kv0 = kcache[base + lane]; kv1 = kcache[base + lane + 64];
      vv0 = vcache[base + lane]; vv1 = vcache[base + lane + 64];
    }
    float s = q0 * kv0 + q1 * kv1;
#pragma unroll
    for (int off = 32; off > 0; off >>= 1) s += __shfl_xor(s, off);
    s *= SCALE_;
    float mnew = fmaxf(m, s);
    float alpha = __expf(m - mnew);
    float p = __expf(s - mnew);
    acc0 = acc0 * alpha + p * vv0;
    acc1 = acc1 * alpha + p * vv1;
    l = l * alpha + p;
    m = mnew;
  }

  __shared__ float sm[4], sl[4], sacc[4][128];
  if (lane == 0) { sm[wave] = m; sl[wave] = l; }
  sacc[wave][lane] = acc0;
  sacc[wave][lane + 64] = acc1;
  __syncthreads();
  if (wave == 0) {
    float M = fmaxf(fmaxf(sm[0], sm[1]), fmaxf(sm[2], sm[3]));
    float L = 0.f, A0 = 0.f, A1 = 0.f;
#pragma unroll
    for (int w = 0; w < 4; ++w) {
      float sc = __expf(sm[w] - M);
      L += sl[w] * sc;
      A0 += sacc[w][lane] * sc;
      A1 += sacc[w][lane + 64] * sc;
    }
    float inv = 1.f / L;
    __hip_bfloat16* outp = attn + (size_t)t * HID_ + h * D_;
    storev(outp + lane, A0 * inv);
    storev(outp + lane + 64, A1 * inv);
  }
}

// ---------------------------------------------------------------------------
extern "C" void kernel_launch(void* const* d_in, const int* in_sizes, int n_in,
                              void* d_out, int out_size, void* d_ws, size_t ws_size,
                              hipStream_t stream) {
  const float* hidden  = (const float*)d_in[0];
  const float* Wq      = (const float*)d_in[1];
  const float* Wk      = (const float*)d_in[2];
  const float* Wv      = (const float*)d_in[3];
  const float* Wo      = (const float*)d_in[4];
  const float* wa_q    = (const float*)d_in[5];
  const float* wb_q    = (const float*)d_in[6];
  const float* wa_k    = (const float*)d_in[7];
  const float* wb_k    = (const float*)d_in[8];
  const float* wa_v    = (const float*)d_in[9];
  const float* wb_v    = (const float*)d_in[10];
  const float* wa_o    = (const float*)d_in[11];
  const float* wb_o    = (const float*)d_in[12];
  const float* k_cache = (const float*)d_in[13];
  const float* v_cache = (const float*)d_in[14];
  const int*   indptr  = (const int*)d_in[15];
  const int*   segment = (const int*)d_in[16];
  const int*   kv_lens = (const int*)d_in[17];
  float* out = (float*)d_out;

  const size_t PROJ = (size_t)T_ * HID_;
  __hip_bfloat16* Xb    = (__hip_bfloat16*)d_ws;
  __hip_bfloat16* qp    = Xb + PROJ;
  __hip_bfloat16* kp    = qp + PROJ;
  __hip_bfloat16* vp    = kp + PROJ;
  __hip_bfloat16* attnb = vp + PROJ;
  __hip_bfloat16* WT4   = attnb + PROJ;                 // 4 * HID_^2 bf16
  float* u_q = (float*)(WT4 + 4 * (size_t)HID_ * HID_);
  float* u_k = u_q + (size_t)T_ * R_;
  float* u_v = u_k + (size_t)T_ * R_;
  float* u_o = u_v + (size_t)T_ * R_;

  const int n4 = (int)(PROJ / 4);

  // independent prep: cast X, transpose all 4 weights, LoRA-down q/k/v
  cast_bf16_kernel<<<(n4 + 255) / 256, 256, 0, stream>>>(hidden, Xb, n4);
  transpose_cast4_kernel<<<dim3(HID_ / 64, HID_ / 64, 4), 256, 0, stream>>>(
      Wq, Wk, Wv, Wo, WT4);
  lora_u_kernel<float><<<dim3(T_, 3), 256, 0, stream>>>(
      hidden, wa_q, wa_k, wa_v, segment, u_q, u_k, u_v);

  // fused QKV projection: 3 matrices x 16 n-tiles x 5 m-tiles = 240 blocks
  gemm_bf16_lora_kernel<__hip_bfloat16><<<dim3(48, 5), 512, 0, stream>>>(
      Xb, WT4, u_q, u_k, u_v, wb_q, wb_k, wb_v, segment, qp, kp, vp, T_);

  attn_prefill_mfma_kernel<<<dim3(DOFF_ / QB, H_), 256, 0, stream>>>(qp, kp, vp, indptr, attnb);
  attn_decode_kernel<<<dim3(H_, BD_), 256, 0, stream>>>(qp, kp, vp, k_cache, v_cache,
                                                        kv_lens, attnb);

  // output projection: 16 n-tiles x 5 m-tiles = 80 blocks
  lora_u_kernel<__hip_bfloat16><<<dim3(T_, 1), 256, 0, stream>>>(
      attnb, wa_o, wa_o, wa_o, segment, u_o, u_o, u_o);
  gemm_bf16_lora_kernel<float><<<dim3(16, 5), 512, 0, stream>>>(
      attnb, WT4 + 3 * (size_t)HID_ * HID_, u_o, u_o, u_o, wb_o, wb_o, wb_o,
      segment, out, out, out, T_);
}

// Round 11
// 727.089 us; speedup vs baseline: 1.1946x; 1.1946x over previous
//
#include <hip/hip_runtime.h>
#include <hip/hip_bf16.h>

#define H_     32
#define D_     128
#define HID_   4096
#define DOFF_  1024
#define BD_    32
#define T_     1056
#define MAXKV_ 513
#define R_     16
#define NA_    4
#define SCALE_ 0.08838834764831845f  /* 1/sqrt(128) */

typedef __attribute__((ext_vector_type(8))) short short8;
typedef __attribute__((ext_vector_type(4))) float f32x4;

__device__ __forceinline__ float toF(float x) { return x; }
__device__ __forceinline__ float toF(__hip_bfloat16 x) { return __bfloat162float(x); }
__device__ __forceinline__ void storev(float* p, float v) { *p = v; }
__device__ __forceinline__ void storev(__hip_bfloat16* p, float v) { *p = __float2bfloat16(v); }

__device__ __forceinline__ void gload16(const void* g, void* l) {
  __builtin_amdgcn_global_load_lds(
      (const __attribute__((address_space(1))) unsigned int*)g,
      (__attribute__((address_space(3))) unsigned int*)l, 16, 0, 0);
}

__device__ __forceinline__ void load4(const float* p, float* v) {
  float4 t = *(const float4*)p;
  v[0] = t.x; v[1] = t.y; v[2] = t.z; v[3] = t.w;
}
__device__ __forceinline__ void load4(const __hip_bfloat16* p, float* v) {
  short4 t = *(const short4*)p;
  const __hip_bfloat16* e = (const __hip_bfloat16*)&t;
  v[0] = toF(e[0]); v[1] = toF(e[1]); v[2] = toF(e[2]); v[3] = toF(e[3]);
}

// ---------------------------------------------------------------------------
// fp32 -> bf16 elementwise cast
// ---------------------------------------------------------------------------
__global__ __launch_bounds__(256) void cast_bf16_kernel(
    const float* __restrict__ X, __hip_bfloat16* __restrict__ Y, int n4) {
  int i = blockIdx.x * 256 + threadIdx.x;
  if (i >= n4) return;
  float4 v = ((const float4*)X)[i];
  __hip_bfloat16 o[4] = {__float2bfloat16(v.x), __float2bfloat16(v.y),
                         __float2bfloat16(v.z), __float2bfloat16(v.w)};
  *(short4*)(Y + (size_t)i * 4) = *(short4*)o;
}

// ---------------------------------------------------------------------------
// 4 weights W[K][N] fp32 -> WT4[z][N][K] bf16 in one launch (grid.z picks W).
// ---------------------------------------------------------------------------
__global__ __launch_bounds__(256) void transpose_cast4_kernel(
    const float* __restrict__ W0, const float* __restrict__ W1,
    const float* __restrict__ W2, const float* __restrict__ W3,
    __hip_bfloat16* __restrict__ WT4) {
  __shared__ float tile[64][65];
  const float* W = blockIdx.z == 0 ? W0 : (blockIdx.z == 1 ? W1
                   : (blockIdx.z == 2 ? W2 : W3));
  __hip_bfloat16* WT = WT4 + (size_t)blockIdx.z * HID_ * HID_;
  int tx = threadIdx.x & 15;   // 4-elem chunk
  int ty = threadIdx.x >> 4;   // 0..15
  int r0 = blockIdx.y * 64, c0 = blockIdx.x * 64;
#pragma unroll
  for (int s = 0; s < 64; s += 16) {
    float4 v = *(const float4*)(W + (size_t)(r0 + ty + s) * HID_ + c0 + tx * 4);
    tile[ty + s][tx * 4 + 0] = v.x;
    tile[ty + s][tx * 4 + 1] = v.y;
    tile[ty + s][tx * 4 + 2] = v.z;
    tile[ty + s][tx * 4 + 3] = v.w;
  }
  __syncthreads();
#pragma unroll
  for (int s = 0; s < 64; s += 16) {
    int c = ty + s;
    __hip_bfloat16 o[4];
#pragma unroll
    for (int e = 0; e < 4; ++e) o[e] = __float2bfloat16(tile[tx * 4 + e][c]);
    *(short4*)(WT + (size_t)(c0 + c) * HID_ + r0 + tx * 4) = *(short4*)o;
  }
}

// ---------------------------------------------------------------------------
// u[t][r] = x[t] . WA[aid(t)][:,r]; blockIdx.y selects which of 3 (WA,U) pairs.
// ---------------------------------------------------------------------------
template <typename XT>
__global__ __launch_bounds__(256) void lora_u_kernel(
    const XT* __restrict__ X, const float* __restrict__ WA0,
    const float* __restrict__ WA1, const float* __restrict__ WA2,
    const int* __restrict__ segment, float* __restrict__ U0,
    float* __restrict__ U1, float* __restrict__ U2) {
  int t = blockIdx.x;
  int tid = threadIdx.x;
  const float* WA = blockIdx.y == 0 ? WA0 : (blockIdx.y == 1 ? WA1 : WA2);
  float* U = blockIdx.y == 0 ? U0 : (blockIdx.y == 1 ? U1 : U2);

  int aid = 0;
#pragma unroll
  for (int i = 1; i < NA_; ++i)
    if (t >= segment[i]) aid = i;

  const XT* x = X + (size_t)t * HID_;
  const float* wa = WA + (size_t)aid * HID_ * R_;

  float part[R_];
#pragma unroll
  for (int r = 0; r < R_; ++r) part[r] = 0.f;

  for (int h = tid * 4; h < HID_; h += 1024) {
    float xv[4];
    load4(x + h, xv);
#pragma unroll
    for (int e = 0; e < 4; ++e) {
      const float* w = wa + (size_t)(h + e) * R_;
#pragma unroll
      for (int r = 0; r < R_; ++r) part[r] += xv[e] * w[r];
    }
  }

  __shared__ float red[256][R_ + 1];
#pragma unroll
  for (int r = 0; r < R_; ++r) red[tid][r] = part[r];
  __syncthreads();
  for (int s = 128; s > 0; s >>= 1) {
    if (tid < s) {
#pragma unroll
      for (int r = 0; r < R_; ++r) red[tid][r] += red[tid + s][r];
    }
    __syncthreads();
  }
  if (tid < R_) U[(size_t)t * R_ + tid] = red[0][tid];
}

// ---------------------------------------------------------------------------
// Split-K GEMM partial: P[w][z][t][n] = Xb[t, kz] . W[kz, n]  (fp32 out).
// bf16 MFMA, 128x128 tile, BK=32, 4 waves, single-buffer (r5 structure).
// blockIdx.x spans nmat*32 n-tiles; blockIdx.z = K-split.
// ---------------------------------------------------------------------------
__global__ __launch_bounds__(256) void gemm_bf16_part_kernel(
    const __hip_bfloat16* __restrict__ Xb, const __hip_bfloat16* __restrict__ WT4,
    float* __restrict__ part, int Trows) {
  __shared__ __hip_bfloat16 As[128 * 32];
  __shared__ __hip_bfloat16 Bs[128 * 32];

  // XCD-aware bijective remap over (x,y); z kept separate
  const int nwg = gridDim.x * gridDim.y;
  const int flat = blockIdx.y * gridDim.x + blockIdx.x;
  const int swz = (flat & 7) * (nwg >> 3) + (flat >> 3);
  const int bx = swz % gridDim.x;
  const int by = swz / gridDim.x;
  const int w = bx >> 5;             // matrix index (32 n-tiles each)
  const int n0 = (bx & 31) * 128;
  const int m0 = by * 128;

  const int klen = HID_ / gridDim.z;
  const int kbase = blockIdx.z * klen;

  const __hip_bfloat16* WT = WT4 + (size_t)w * HID_ * HID_;
  float* P = part + ((size_t)w * gridDim.z + blockIdx.z) * ((size_t)T_ * HID_);

  const int tid = threadIdx.x;
  const int lane = tid & 63;
  const int wave = tid >> 6;
  const int wr = (wave >> 1) * 64;
  const int wc = (wave & 1) * 64;

  const int srow = tid >> 2;
  const int sel = (tid & 3) * 8;
  int ar0 = m0 + srow;      if (ar0 >= Trows) ar0 = Trows - 1;
  int ar1 = m0 + srow + 64; if (ar1 >= Trows) ar1 = Trows - 1;
  const __hip_bfloat16* gA0 = Xb + (size_t)ar0 * HID_ + kbase + sel;
  const __hip_bfloat16* gA1 = Xb + (size_t)ar1 * HID_ + kbase + sel;
  const __hip_bfloat16* gB0 = WT + (size_t)(n0 + srow) * HID_ + kbase + sel;
  const __hip_bfloat16* gB1 = WT + (size_t)(n0 + srow + 64) * HID_ + kbase + sel;
  __hip_bfloat16* lA = As + tid * 8;
  __hip_bfloat16* lB = Bs + tid * 8;

  const int lrow = lane & 15;
  const int lk = (lane >> 4) * 8;
  const __hip_bfloat16* fA = As + (wr + lrow) * 32 + lk;
  const __hip_bfloat16* fB = Bs + (wc + lrow) * 32 + lk;

  f32x4 acc[4][4] = {};

  for (int k0 = 0; k0 < klen; k0 += 32) {
    gload16(gA0, lA);
    gload16(gA1, lA + 2048);
    gload16(gB0, lB);
    gload16(gB1, lB + 2048);
    gA0 += 32; gA1 += 32; gB0 += 32; gB1 += 32;
    __syncthreads();
    short8 a[4], b[4];
#pragma unroll
    for (int mi = 0; mi < 4; ++mi) a[mi] = *(const short8*)(fA + mi * 512);
#pragma unroll
    for (int ni = 0; ni < 4; ++ni) b[ni] = *(const short8*)(fB + ni * 512);
#pragma unroll
    for (int mi = 0; mi < 4; ++mi)
#pragma unroll
      for (int ni = 0; ni < 4; ++ni)
        acc[mi][ni] = __builtin_amdgcn_mfma_f32_16x16x32_bf16(a[mi], b[ni], acc[mi][ni], 0, 0, 0);
    __syncthreads();
  }

  const int crow = (lane >> 4) * 4;
  const int ccol = lane & 15;
#pragma unroll
  for (int mi = 0; mi < 4; ++mi) {
    const int tb = m0 + wr + mi * 16 + crow;
#pragma unroll
    for (int i = 0; i < 4; ++i) {
      const int t = tb + i;
      if (t >= Trows) continue;
#pragma unroll
      for (int ni = 0; ni < 4; ++ni) {
        const int n = n0 + wc + ni * 16 + ccol;
        P[(size_t)t * HID_ + n] = acc[mi][ni][i];
      }
    }
  }
}

// ---------------------------------------------------------------------------
// Reduce split-K partials + segmented LoRA up-proj + cast/store.
// part layout: [mat][NS][T_][HID_]; grid = (T_, nmat).
// ---------------------------------------------------------------------------
template <typename OUT_T, int NS>
__global__ __launch_bounds__(256) void reduce_lora_kernel(
    const float* __restrict__ part, const float* __restrict__ U0,
    const float* __restrict__ U1, const float* __restrict__ U2,
    const float* __restrict__ B0, const float* __restrict__ B1,
    const float* __restrict__ B2, const int* __restrict__ segment,
    OUT_T* __restrict__ Y0, OUT_T* __restrict__ Y1, OUT_T* __restrict__ Y2) {
  const int t = blockIdx.x;
  const int mat = blockIdx.y;
  const int tid = threadIdx.x;

  const float* U = mat == 0 ? U0 : (mat == 1 ? U1 : U2);
  const float* B = mat == 0 ? B0 : (mat == 1 ? B1 : B2);
  OUT_T* Y = mat == 0 ? Y0 : (mat == 1 ? Y1 : Y2);

  int aid = 0;
#pragma unroll
  for (int i = 1; i < NA_; ++i)
    if (t >= segment[i]) aid = i;

  float u[R_];
#pragma unroll
  for (int r = 0; r < R_; ++r) u[r] = U[(size_t)t * R_ + r];

  const size_t pstride = (size_t)T_ * HID_;
  const float* pbase = part + (size_t)mat * NS * pstride + (size_t)t * HID_;
  const float* bbase = B + (size_t)aid * R_ * HID_;
  OUT_T* ybase = Y + (size_t)t * HID_;

  for (int j = tid; j < HID_ / 4; j += 256) {
    const int n = j * 4;
    float4 acc = *(const float4*)(pbase + n);
#pragma unroll
    for (int s = 1; s < NS; ++s) {
      float4 p = *(const float4*)(pbase + s * pstride + n);
      acc.x += p.x; acc.y += p.y; acc.z += p.z; acc.w += p.w;
    }
#pragma unroll
    for (int r = 0; r < R_; ++r) {
      float4 b = *(const float4*)(bbase + (size_t)r * HID_ + n);
      acc.x += u[r] * b.x; acc.y += u[r] * b.y;
      acc.z += u[r] * b.z; acc.w += u[r] * b.w;
    }
    storev(ybase + n + 0, acc.x);
    storev(ybase + n + 1, acc.y);
    storev(ybase + n + 2, acc.z);
    storev(ybase + n + 3, acc.w);
  }
}

// ---------------------------------------------------------------------------
// MFMA flash prefill. Block = 64 queries x 1 head, 4 waves x 16 q-rows.
// ---------------------------------------------------------------------------
#define QB 64
#define KB 32

__global__ __launch_bounds__(256) void attn_prefill_mfma_kernel(
    const __hip_bfloat16* __restrict__ qp, const __hip_bfloat16* __restrict__ kp,
    const __hip_bfloat16* __restrict__ vp, const int* __restrict__ indptr,
    __hip_bfloat16* __restrict__ attn) {
  __shared__ __hip_bfloat16 Klds[KB * 128];     // XOR-swizzled (chunk ^= row&7)
  __shared__ __hip_bfloat16 Vt[128 * 40];       // Vt[d][k], rows padded to 40
  __shared__ __hip_bfloat16 Plds[4][16 * 40];   // per-wave P, rows padded to 40

  const int nwg = gridDim.x * gridDim.y;
  const int flat = blockIdx.y * gridDim.x + blockIdx.x;
  const int swz = (flat & 7) * (nwg >> 3) + (flat >> 3);
  const int q0 = (swz % gridDim.x) * QB;
  const int h = swz / gridDim.x;

  const int tid = threadIdx.x;
  const int lane = tid & 63;
  const int wave = tid >> 6;
  const int g = lane >> 4;
  const int lc = lane & 15;

  int qrows[4], qstart[4];
#pragma unroll
  for (int i = 0; i < 4; ++i) {
    int q = q0 + wave * 16 + g * 4 + i;
    qrows[i] = q;
    int s0 = 0;
#pragma unroll
    for (int j = 1; j < NA_; ++j)
      if (q >= indptr[j]) s0 = indptr[j];
    qstart[i] = s0;
  }

  short8 aq[4];
  {
    const __hip_bfloat16* qrow = qp + (size_t)(q0 + wave * 16 + lc) * HID_ + h * D_;
#pragma unroll
    for (int dc = 0; dc < 4; ++dc)
      aq[dc] = *(const short8*)(qrow + dc * 32 + g * 8);
  }

  float mrow[4], lrow[4];
#pragma unroll
  for (int i = 0; i < 4; ++i) { mrow[i] = -1e30f; lrow[i] = 0.f; }
  f32x4 o[8] = {};

  int ks0 = 0;
#pragma unroll
  for (int j = 1; j < NA_; ++j)
    if (q0 >= indptr[j]) ks0 = indptr[j];
  const int kt0 = ks0 & ~(KB - 1);

  const int sr = tid >> 4;
  const int sc = tid & 15;

  for (int kt = kt0; kt < q0 + QB; kt += KB) {
    gload16(kp + (size_t)(kt + sr) * HID_ + h * D_ + ((sc ^ (sr & 7)) * 8),
            Klds + tid * 8);
    gload16(kp + (size_t)(kt + 16 + sr) * HID_ + h * D_ + ((sc ^ (sr & 7)) * 8),
            Klds + 2048 + tid * 8);
    {
      short8 v0 = *(const short8*)(vp + (size_t)(kt + sr) * HID_ + h * D_ + sc * 8);
      short8 v1 = *(const short8*)(vp + (size_t)(kt + 16 + sr) * HID_ + h * D_ + sc * 8);
      const __hip_bfloat16* e0 = (const __hip_bfloat16*)&v0;
      const __hip_bfloat16* e1 = (const __hip_bfloat16*)&v1;
#pragma unroll
      for (int e = 0; e < 8; ++e) {
        Vt[(sc * 8 + e) * 40 + sr] = e0[e];
        Vt[(sc * 8 + e) * 40 + sr + 16] = e1[e];
      }
    }
    __syncthreads();

    f32x4 s0v = {}, s1v = {};
#pragma unroll
    for (int dc = 0; dc < 4; ++dc) {
      const int cb = dc * 4 + g;
      short8 bk0 = *(const short8*)(Klds + lc * 128 + ((cb ^ (lc & 7)) * 8));
      short8 bk1 = *(const short8*)(Klds + (16 + lc) * 128 + ((cb ^ (lc & 7)) * 8));
      s0v = __builtin_amdgcn_mfma_f32_16x16x32_bf16(aq[dc], bk0, s0v, 0, 0, 0);
      s1v = __builtin_amdgcn_mfma_f32_16x16x32_bf16(aq[dc], bk1, s1v, 0, 0, 0);
    }

    const int kl0 = kt + lc, kl1 = kt + 16 + lc;
#pragma unroll
    for (int i = 0; i < 4; ++i) {
      float sm0 = s0v[i] * SCALE_;
      float sm1 = s1v[i] * SCALE_;
      bool v0ok = (kl0 >= qstart[i]) && (kl0 <= qrows[i]);
      bool v1ok = (kl1 >= qstart[i]) && (kl1 <= qrows[i]);
      float mx = fmaxf(v0ok ? sm0 : -1e30f, v1ok ? sm1 : -1e30f);
#pragma unroll
      for (int off = 1; off < 16; off <<= 1)
        mx = fmaxf(mx, __shfl_xor(mx, off));
      float mnew = fmaxf(mrow[i], mx);
      float alpha = __expf(mrow[i] - mnew);
      float p0 = v0ok ? __expf(sm0 - mnew) : 0.f;
      float p1 = v1ok ? __expf(sm1 - mnew) : 0.f;
      lrow[i] = lrow[i] * alpha + p0 + p1;
      mrow[i] = mnew;
#pragma unroll
      for (int dc = 0; dc < 8; ++dc) o[dc][i] *= alpha;
      Plds[wave][(g * 4 + i) * 40 + lc] = __float2bfloat16(p0);
      Plds[wave][(g * 4 + i) * 40 + 16 + lc] = __float2bfloat16(p1);
    }

    asm volatile("s_waitcnt lgkmcnt(0)" ::: "memory");

    short8 ap = *(const short8*)(&Plds[wave][lc * 40 + g * 8]);
#pragma unroll
    for (int dc = 0; dc < 8; ++dc) {
      short8 bv = *(const short8*)(&Vt[(dc * 16 + lc) * 40 + g * 8]);
      o[dc] = __builtin_amdgcn_mfma_f32_16x16x32_bf16(ap, bv, o[dc], 0, 0, 0);
    }
    __syncthreads();
  }

#pragma unroll
  for (int i = 0; i < 4; ++i) {
    float l = lrow[i];
#pragma unroll
    for (int off = 1; off < 16; off <<= 1) l += __shfl_xor(l, off);
    lrow[i] = 1.f / l;
  }
#pragma unroll
  for (int dc = 0; dc < 8; ++dc)
#pragma unroll
    for (int i = 0; i < 4; ++i)
      attn[(size_t)qrows[i] * HID_ + h * D_ + dc * 16 + lc] =
          __float2bfloat16(o[dc][i] * lrow[i]);
}

// ---------------------------------------------------------------------------
// Paged decode attention (4 waves split keys; appended token from kp/vp).
// ---------------------------------------------------------------------------
__global__ __launch_bounds__(256) void attn_decode_kernel(
    const __hip_bfloat16* __restrict__ qp, const __hip_bfloat16* __restrict__ kp,
    const __hip_bfloat16* __restrict__ vp, const float* __restrict__ kcache,
    const float* __restrict__ vcache, const int* __restrict__ kv_lens,
    __hip_bfloat16* __restrict__ attn) {
  int h = blockIdx.x;
  int b = blockIdx.y;
  int wave = threadIdx.x >> 6;
  int lane = threadIdx.x & 63;
  int t = DOFF_ + b;

  const __hip_bfloat16* qptr = qp + (size_t)t * HID_ + h * D_;
  float q0 = toF(qptr[lane]), q1 = toF(qptr[lane + 64]);
  int len = kv_lens[b];

  int cnt = len + 1;
  int chunk = (cnt + 3) >> 2;
  int ks = wave * chunk;
  int ke = ks + chunk; if (ke > cnt) ke = cnt;

  float m = -1e30f, l = 0.f, acc0 = 0.f, acc1 = 0.f;
  for (int k = ks; k < ke; ++k) {
    float kv0, kv1, vv0, vv1;
    if (k == len) {
      const __hip_bfloat16* kptr = kp + (size_t)t * HID_ + h * D_;
      const __hip_bfloat16* vptr = vp + (size_t)t * HID_ + h * D_;
      kv0 = toF(kptr[lane]); kv1 = toF(kptr[lane + 64]);
      vv0 = toF(vptr[lane]); vv1 = toF(vptr[lane + 64]);
    } else {
      size_t base = (((size_t)b * MAXKV_ + k) * H_ + h) * D_;
      kv0 = kcache[base + lane]; kv1 = kcache[base + lane + 64];
      vv0 = vcache[base + lane]; vv1 = vcache[base + lane + 64];
    }
    float s = q0 * kv0 + q1 * kv1;
#pragma unroll
    for (int off = 32; off > 0; off >>= 1) s += __shfl_xor(s, off);
    s *= SCALE_;
    float mnew = fmaxf(m, s);
    float alpha = __expf(m - mnew);
    float p = __expf(s - mnew);
    acc0 = acc0 * alpha + p * vv0;
    acc1 = acc1 * alpha + p * vv1;
    l = l * alpha + p;
    m = mnew;
  }

  __shared__ float sm[4], sl[4], sacc[4][128];
  if (lane == 0) { sm[wave] = m; sl[wave] = l; }
  sacc[wave][lane] = acc0;
  sacc[wave][lane + 64] = acc1;
  __syncthreads();
  if (wave == 0) {
    float M = fmaxf(fmaxf(sm[0], sm[1]), fmaxf(sm[2], sm[3]));
    float L = 0.f, A0 = 0.f, A1 = 0.f;
#pragma unroll
    for (int w = 0; w < 4; ++w) {
      float sc = __expf(sm[w] - M);
      L += sl[w] * sc;
      A0 += sacc[w][lane] * sc;
      A1 += sacc[w][lane + 64] * sc;
    }
    float inv = 1.f / L;
    __hip_bfloat16* outp = attn + (size_t)t * HID_ + h * D_;
    storev(outp + lane, A0 * inv);
    storev(outp + lane + 64, A1 * inv);
  }
}

// ---------------------------------------------------------------------------
extern "C" void kernel_launch(void* const* d_in, const int* in_sizes, int n_in,
                              void* d_out, int out_size, void* d_ws, size_t ws_size,
                              hipStream_t stream) {
  const float* hidden  = (const float*)d_in[0];
  const float* Wq      = (const float*)d_in[1];
  const float* Wk      = (const float*)d_in[2];
  const float* Wv      = (const float*)d_in[3];
  const float* Wo      = (const float*)d_in[4];
  const float* wa_q    = (const float*)d_in[5];
  const float* wb_q    = (const float*)d_in[6];
  const float* wa_k    = (const float*)d_in[7];
  const float* wb_k    = (const float*)d_in[8];
  const float* wa_v    = (const float*)d_in[9];
  const float* wb_v    = (const float*)d_in[10];
  const float* wa_o    = (const float*)d_in[11];
  const float* wb_o    = (const float*)d_in[12];
  const float* k_cache = (const float*)d_in[13];
  const float* v_cache = (const float*)d_in[14];
  const int*   indptr  = (const int*)d_in[15];
  const int*   segment = (const int*)d_in[16];
  const int*   kv_lens = (const int*)d_in[17];
  float* out = (float*)d_out;

  const size_t PROJ = (size_t)T_ * HID_;
  __hip_bfloat16* Xb    = (__hip_bfloat16*)d_ws;
  __hip_bfloat16* qp    = Xb + PROJ;
  __hip_bfloat16* kp    = qp + PROJ;
  __hip_bfloat16* vp    = kp + PROJ;
  __hip_bfloat16* attnb = vp + PROJ;
  __hip_bfloat16* WT4   = attnb + PROJ;                 // 4 * HID_^2 bf16
  float* u_q = (float*)(WT4 + 4 * (size_t)HID_ * HID_);
  float* u_k = u_q + (size_t)T_ * R_;
  float* u_v = u_k + (size_t)T_ * R_;
  float* u_o = u_v + (size_t)T_ * R_;
  float* partb = u_o + (size_t)T_ * R_;                 // 6 * PROJ fp32 (104 MB)

  const int n4 = (int)(PROJ / 4);

  // independent prep: cast X, transpose all 4 weights, LoRA-down q/k/v
  cast_bf16_kernel<<<(n4 + 255) / 256, 256, 0, stream>>>(hidden, Xb, n4);
  transpose_cast4_kernel<<<dim3(HID_ / 64, HID_ / 64, 4), 256, 0, stream>>>(
      Wq, Wk, Wv, Wo, WT4);
  lora_u_kernel<float><<<dim3(T_, 3), 256, 0, stream>>>(
      hidden, wa_q, wa_k, wa_v, segment, u_q, u_k, u_v);

  // fused QKV projection, split-K=2: 96x9x2 = 1728 blocks
  gemm_bf16_part_kernel<<<dim3(96, 9, 2), 256, 0, stream>>>(Xb, WT4, partb, T_);
  reduce_lora_kernel<__hip_bfloat16, 2><<<dim3(T_, 3), 256, 0, stream>>>(
      partb, u_q, u_k, u_v, wb_q, wb_k, wb_v, segment, qp, kp, vp);

  attn_prefill_mfma_kernel<<<dim3(DOFF_ / QB, H_), 256, 0, stream>>>(qp, kp, vp, indptr, attnb);
  attn_decode_kernel<<<dim3(H_, BD_), 256, 0, stream>>>(qp, kp, vp, k_cache, v_cache,
                                                        kv_lens, attnb);

  // output projection, split-K=4: 32x9x4 = 1152 blocks
  lora_u_kernel<__hip_bfloat16><<<dim3(T_, 1), 256, 0, stream>>>(
      attnb, wa_o, wa_o, wa_o, segment, u_o, u_o, u_o);
  gemm_bf16_part_kernel<<<dim3(32, 9, 4), 256, 0, stream>>>(
      attnb, WT4 + 3 * (size_t)HID_ * HID_, partb, T_);
  reduce_lora_kernel<float, 4><<<dim3(T_, 1), 256, 0, stream>>>(
      partb, u_o, u_o, u_o, wb_o, wb_o, wb_o, segment, out, out, out);
}